// Round 5
// baseline (254.322 us; speedup 1.0000x reference)
//
#include <hip/hip_runtime.h>

// YOLO-v1 loss, fp32, N=16384, S=7, B=2, C=20 → 30 floats/cell, 802816 cells.
// R5: MLP fix. R1-R4 all pinned at 70-79 µs (~2.7 TB/s effective read) with
// an issue-burst → vmcnt(0)-drain → die wave shape. This version uses
// persistent waves (2048 waves, ~6 64-cell tiles each) with register
// ping-pong prefetch: tile k+1's 16 float4 loads are issued BEFORE tile k is
// consumed, so register dependency tracking gives partial vmcnt waits and
// loads stay continuously in flight. Per-wave accumulator, one store/wave.

constexpr int S = 7;
constexpr int FPC = 30;             // floats per cell
constexpr int BLK = 256;            // 4 waves/block
constexpr int NBLOCKS = 512;
constexpr int NWAVES = NBLOCKS * (BLK / 64);   // 2048
constexpr int TILE_F4 = 64 * FPC / 4;          // 480 float4 per 64-cell tile
constexpr int NTILES = 802816 / 64;            // 12544
constexpr float STEP = 1.0f / 7.0f;
constexpr float EPS = 1e-10f;

__device__ __forceinline__ void issue_tile(const float* __restrict__ pred,
                                           const float* __restrict__ target,
                                           int tile, int lane,
                                           float4* rp, float4* rt) {
  const float4* gp = (const float4*)(pred + (size_t)tile * 64 * FPC);
  const float4* gt = (const float4*)(target + (size_t)tile * 64 * FPC);
  #pragma unroll
  for (int i = 0; i < 8; ++i) {
    int idx = i * 64 + lane;
    if (idx < TILE_F4) {
      rp[i] = gp[idx];
      rt[i] = gt[idx];
    }
  }
}

__device__ __forceinline__ float process_tile(float* myld, int tile, int lane,
                                              const float4* rp, const float4* rt) {
  float4* l4 = (float4*)myld;
  union Buf { float2 v[FPC / 2]; float f[FPC]; };
  Buf P, T;
  const float2* l2 = (const float2*)(myld + lane * FPC);

  // pred: regs → LDS → per-cell regs (DS ops in-order within a wave)
  #pragma unroll
  for (int i = 0; i < 8; ++i) {
    int idx = i * 64 + lane;
    if (idx < TILE_F4) l4[idx] = rp[i];
  }
  #pragma unroll
  for (int i = 0; i < FPC / 2; ++i) P.v[i] = l2[i];
  asm volatile("" ::: "memory");  // keep target writes after pred reads
  // target into the SAME wave-private region
  #pragma unroll
  for (int i = 0; i < 8; ++i) {
    int idx = i * 64 + lane;
    if (idx < TILE_F4) l4[idx] = rt[i];
  }
  #pragma unroll
  for (int i = 0; i < FPC / 2; ++i) T.v[i] = l2[i];
  asm volatile("" ::: "memory");  // keep next tile's writes after these reads

  const float* p = P.f;
  const float* t = T.f;
  const int cell = tile * 64 + lane;
  const float gx = (float)(cell % S);
  const float gy = (float)((cell / S) % S);
  const float mask = (t[9] > 0.0f) ? 1.0f : 0.0f;

  float iou[2];
  #pragma unroll
  for (int b = 0; b < 2; ++b) {
    const float* pb = p + 5 * b;
    const float* tb = t + 5 * b;
    float px = fmaxf((pb[0] + gx) * STEP - pb[2] * 0.5f, 0.0f);
    float py = fmaxf((pb[1] + gy) * STEP - pb[3] * 0.5f, 0.0f);
    float pw = fmaxf(pb[2], 0.0f);
    float ph = fmaxf(pb[3], 0.0f);
    float tx = fmaxf((tb[0] + gx) * STEP - tb[2] * 0.5f, 0.0f);
    float ty = fmaxf((tb[1] + gy) * STEP - tb[3] * 0.5f, 0.0f);
    float tw = fmaxf(tb[2], 0.0f);
    float th = fmaxf(tb[3], 0.0f);
    float iw = fmaxf(pw + tw - (fmaxf(px + pw, tx + tw) - fminf(px, tx)), 0.0f);
    float ih = fmaxf(ph + th - (fmaxf(py + ph, ty + th) - fminf(py, ty)), 0.0f);
    float inter = iw * ih;
    float uni = pw * ph + tw * th - inter;
    iou[b] = inter / (uni + EPS);
  }
  const int best = (iou[1] > iou[0]) ? 1 : 0;  // argmax: first max wins

  float loss = 0.0f;
  #pragma unroll
  for (int b = 0; b < 2; ++b) {
    const float* pb = p + 5 * b;
    const float* tb = t + 5 * b;
    float obj = (b == best) ? mask : 0.0f;
    float d0 = pb[0] - tb[0];
    float d1 = pb[1] - tb[1];
    float d2 = pb[2] - tb[2];
    float d3 = pb[3] - tb[3];
    loss += 5.0f * obj * (d0 * d0 + d1 * d1 + d2 * d2 + d3 * d3);  // coord
    float dc = pb[4] - iou[b];
    loss += obj * dc * dc;                                         // conf
    loss += 0.5f * (1.0f - obj) * pb[4] * pb[4];                   // noobj
  }
  float cls = 0.0f;
  #pragma unroll
  for (int k = 10; k < 30; ++k) {
    float d = p[k] - t[k];
    cls += d * d;
  }
  loss += mask * cls;                                              // class
  return loss;
}

__global__ __launch_bounds__(BLK) void yolo_partial_kernel(
    const float* __restrict__ pred,
    const float* __restrict__ target,
    float* __restrict__ partial) {
  __shared__ float lds[BLK / 64][64 * FPC];   // 7680 B per wave region

  const int tid = threadIdx.x;
  const int lane = tid & 63;
  const int wid = tid >> 6;
  const int gw = blockIdx.x * (BLK / 64) + wid;   // global wave id
  float* myld = lds[wid];

  float4 Ap[8], At[8], Bp[8], Bt[8];
  float acc = 0.0f;

  int tile = gw;
  bool more = (tile < NTILES);
  if (more) issue_tile(pred, target, tile, lane, Ap, At);
  while (more) {
    int nxt = tile + NWAVES;
    bool moreB = (nxt < NTILES);
    if (moreB) issue_tile(pred, target, nxt, lane, Bp, Bt);   // prefetch
    acc += process_tile(myld, tile, lane, Ap, At);
    if (!moreB) break;
    int nxt2 = nxt + NWAVES;
    bool moreA = (nxt2 < NTILES);
    if (moreA) issue_tile(pred, target, nxt2, lane, Ap, At);  // prefetch
    acc += process_tile(myld, nxt, lane, Bp, Bt);
    tile = nxt2;
    more = moreA;
  }

  // per-wave reduce → one plain store per wave
  #pragma unroll
  for (int off = 32; off > 0; off >>= 1)
    acc += __shfl_down(acc, off, 64);
  if (lane == 0) partial[gw] = acc;
}

__global__ __launch_bounds__(256) void yolo_reduce_kernel(
    const float* __restrict__ partial, float* __restrict__ out,
    int n, float invN) {
  __shared__ float wsum[4];
  const int tid = threadIdx.x;
  float s = 0.0f;
  for (int i = tid; i < n; i += 256) s += partial[i];
  #pragma unroll
  for (int off = 32; off > 0; off >>= 1)
    s += __shfl_down(s, off, 64);
  if ((tid & 63) == 0) wsum[tid >> 6] = s;
  __syncthreads();
  if (tid == 0)
    out[0] = (wsum[0] + wsum[1] + wsum[2] + wsum[3]) * invN;
}

extern "C" void kernel_launch(void* const* d_in, const int* in_sizes, int n_in,
                              void* d_out, int out_size, void* d_ws, size_t ws_size,
                              hipStream_t stream) {
  const float* pred = (const float*)d_in[0];
  const float* target = (const float*)d_in[1];
  float* out = (float*)d_out;
  float* partial = (float*)d_ws;             // 2048 floats = 8 KB

  const int ncells = in_sizes[0] / FPC;      // 802816
  const float invN = 1.0f / (float)(ncells / (S * S));  // 1/16384

  yolo_partial_kernel<<<NBLOCKS, BLK, 0, stream>>>(pred, target, partial);
  yolo_reduce_kernel<<<1, 256, 0, stream>>>(partial, out, NWAVES, invN);
}

// Round 6
// 203.169 us; speedup vs baseline: 1.2518x; 1.2518x over previous
//
#include <hip/hip_runtime.h>

// YOLO-v1 loss, fp32, N=16384, S=7, B=2, C=20 → 30 floats/cell, 802816 cells.
// R6: deep MLP via global_load_lds (async global→LDS, no VGPR round-trip —
// R5's register prefetch was spilled to scratch by the compiler: VGPR=48,
// WRITE_SIZE 188 MB). Persistent waves, wave-PRIVATE double-buffered LDS
// (no __syncthreads in the loop → no compiler-forced vmcnt(0) barrier
// drain; we control waits with explicit s_waitcnt vmcnt(16)).
// Per wave: 2 bufs × (pred 7680 B + target 7680 B) = 30.7 KB; BLK=128
// → 61.4 KB/block, 2 blocks/CU, 4 waves/CU, 64 KB in flight per CU.

constexpr int S = 7;
constexpr int FPC = 30;              // floats per cell
constexpr int BLK = 128;             // 2 waves/block
constexpr int NBLOCKS = 512;
constexpr int NWAVES = NBLOCKS * (BLK / 64);   // 1024
constexpr int TILE_FLOATS = 64 * FPC;          // 1920 floats = 7680 B
constexpr int NTILES = 802816 / 64;            // 12544
constexpr float STEP = 1.0f / 7.0f;
constexpr float EPS = 1e-10f;

__device__ __forceinline__ void async16(const float* g, float* l) {
  __builtin_amdgcn_global_load_lds(
      (const __attribute__((address_space(1))) void*)g,
      (__attribute__((address_space(3))) void*)l, 16, 0, 0);
}

// Stage one 64-cell tile (7680 B) of `src` into wave-uniform ldsbase.
// 8 VMEM instrs: 7 full 1024-B chunks + one 512-B half-wave chunk.
__device__ __forceinline__ void stage_tile(const float* __restrict__ src,
                                           int tile, float* ldsbase, int lane) {
  const float* g = src + (size_t)tile * TILE_FLOATS + lane * 4;
  #pragma unroll
  for (int c = 0; c < 7; ++c)
    async16(g + c * 256, ldsbase + c * 256);
  if (lane < 32)
    async16(g + 7 * 256, ldsbase + 7 * 256);
}

__device__ __forceinline__ float cell_loss(const float* __restrict__ bp,
                                           const float* __restrict__ bt,
                                           int tile, int lane) {
  union Buf { float2 v[FPC / 2]; float f[FPC]; };
  Buf P, T;
  const float2* p2 = (const float2*)(bp + lane * FPC);
  const float2* t2 = (const float2*)(bt + lane * FPC);
  #pragma unroll
  for (int i = 0; i < FPC / 2; ++i) P.v[i] = p2[i];
  #pragma unroll
  for (int i = 0; i < FPC / 2; ++i) T.v[i] = t2[i];
  const float* p = P.f;
  const float* t = T.f;

  const int cell = tile * 64 + lane;
  const float gx = (float)(cell % S);
  const float gy = (float)((cell / S) % S);
  const float mask = (t[9] > 0.0f) ? 1.0f : 0.0f;

  float iou[2];
  #pragma unroll
  for (int b = 0; b < 2; ++b) {
    const float* pb = p + 5 * b;
    const float* tb = t + 5 * b;
    float px = fmaxf((pb[0] + gx) * STEP - pb[2] * 0.5f, 0.0f);
    float py = fmaxf((pb[1] + gy) * STEP - pb[3] * 0.5f, 0.0f);
    float pw = fmaxf(pb[2], 0.0f);
    float ph = fmaxf(pb[3], 0.0f);
    float tx = fmaxf((tb[0] + gx) * STEP - tb[2] * 0.5f, 0.0f);
    float ty = fmaxf((tb[1] + gy) * STEP - tb[3] * 0.5f, 0.0f);
    float tw = fmaxf(tb[2], 0.0f);
    float th = fmaxf(tb[3], 0.0f);
    float iw = fmaxf(pw + tw - (fmaxf(px + pw, tx + tw) - fminf(px, tx)), 0.0f);
    float ih = fmaxf(ph + th - (fmaxf(py + ph, ty + th) - fminf(py, ty)), 0.0f);
    float inter = iw * ih;
    float uni = pw * ph + tw * th - inter;
    iou[b] = inter / (uni + EPS);
  }
  const int best = (iou[1] > iou[0]) ? 1 : 0;  // argmax: first max wins

  float loss = 0.0f;
  #pragma unroll
  for (int b = 0; b < 2; ++b) {
    const float* pb = p + 5 * b;
    const float* tb = t + 5 * b;
    float obj = (b == best) ? mask : 0.0f;
    float d0 = pb[0] - tb[0];
    float d1 = pb[1] - tb[1];
    float d2 = pb[2] - tb[2];
    float d3 = pb[3] - tb[3];
    loss += 5.0f * obj * (d0 * d0 + d1 * d1 + d2 * d2 + d3 * d3);  // coord
    float dc = pb[4] - iou[b];
    loss += obj * dc * dc;                                         // conf
    loss += 0.5f * (1.0f - obj) * pb[4] * pb[4];                   // noobj
  }
  float cls = 0.0f;
  #pragma unroll
  for (int k = 10; k < 30; ++k) {
    float d = p[k] - t[k];
    cls += d * d;
  }
  loss += mask * cls;                                              // class
  return loss;
}

__global__ __launch_bounds__(BLK) void yolo_partial_kernel(
    const float* __restrict__ pred,
    const float* __restrict__ target,
    float* __restrict__ partial) {
  // [wave][buf][array(pred/target)][1920 floats]
  __shared__ float lds[BLK / 64][2][2][TILE_FLOATS];   // 61440 B

  const int tid = threadIdx.x;
  const int lane = tid & 63;
  const int wid = tid >> 6;
  const int gw = blockIdx.x * (BLK / 64) + wid;   // global wave id 0..1023

  float acc = 0.0f;
  int buf = 0;

  // prologue: stage first tile into buf 0
  int t0 = gw;
  stage_tile(pred, t0, lds[wid][0][0], lane);
  stage_tile(target, t0, lds[wid][0][1], lane);

  for (int tile = t0; tile < NTILES; tile += NWAVES) {
    const int nxt = tile + NWAVES;
    const bool has_next = (nxt < NTILES);
    if (has_next) {   // prefetch next tile into the other buffer (+16 instrs)
      stage_tile(pred, nxt, lds[wid][buf ^ 1][0], lane);
      stage_tile(target, nxt, lds[wid][buf ^ 1][1], lane);
      // drain current tile's 16 loads; keep next tile's 16 in flight
      asm volatile("s_waitcnt vmcnt(16)" ::: "memory");
    } else {
      asm volatile("s_waitcnt vmcnt(0)" ::: "memory");
    }
    acc += cell_loss(lds[wid][buf][0], lds[wid][buf][1], tile, lane);
    asm volatile("" ::: "memory");  // keep next iter's stores after these reads
    buf ^= 1;
  }

  // per-wave reduce → one plain store per wave
  #pragma unroll
  for (int off = 32; off > 0; off >>= 1)
    acc += __shfl_down(acc, off, 64);
  if (lane == 0) partial[gw] = acc;
}

__global__ __launch_bounds__(256) void yolo_reduce_kernel(
    const float* __restrict__ partial, float* __restrict__ out,
    int n, float invN) {
  __shared__ float wsum[4];
  const int tid = threadIdx.x;
  float s = 0.0f;
  for (int i = tid; i < n; i += 256) s += partial[i];
  #pragma unroll
  for (int off = 32; off > 0; off >>= 1)
    s += __shfl_down(s, off, 64);
  if ((tid & 63) == 0) wsum[tid >> 6] = s;
  __syncthreads();
  if (tid == 0)
    out[0] = (wsum[0] + wsum[1] + wsum[2] + wsum[3]) * invN;
}

extern "C" void kernel_launch(void* const* d_in, const int* in_sizes, int n_in,
                              void* d_out, int out_size, void* d_ws, size_t ws_size,
                              hipStream_t stream) {
  const float* pred = (const float*)d_in[0];
  const float* target = (const float*)d_in[1];
  float* out = (float*)d_out;
  float* partial = (float*)d_ws;             // 1024 floats = 4 KB

  const int ncells = in_sizes[0] / FPC;      // 802816
  const float invN = 1.0f / (float)(ncells / (S * S));  // 1/16384

  yolo_partial_kernel<<<NBLOCKS, BLK, 0, stream>>>(pred, target, partial);
  yolo_reduce_kernel<<<1, 256, 0, stream>>>(partial, out, NWAVES, invN);
}

// Round 8
// 188.420 us; speedup vs baseline: 1.3498x; 1.0783x over previous
//
#include <hip/hip_runtime.h>

// YOLO-v1 loss, fp32, N=16384, S=7, B=2, C=20 → 30 floats/cell, 802816 cells.
// R8 = R7 with compile fix: __builtin_nontemporal_load needs a clang
// ext_vector_type pointer, not HIP_vector_type<float,4>. NT-load A/B test on
// the R4 structure (wave-private LDS staging, dense 16B loads, no atomics).
// Five structures (R1-R6) all pin at ~2.7 TB/s effective read
// (~1.1 L2-line-fills/cyc/XCD). NT is the last lever; if neutral → roofline.

typedef float vfloat4 __attribute__((ext_vector_type(4)));

constexpr int S = 7;
constexpr int FPC = 30;           // floats per cell
constexpr int BLK = 256;          // 4 waves
constexpr int WAVES = BLK / 64;
constexpr int TILE_F4 = 64 * FPC / 4;   // 480 float4 per wave tile
constexpr float STEP = 1.0f / 7.0f;
constexpr float EPS = 1e-10f;

__global__ __launch_bounds__(BLK) void yolo_partial_kernel(
    const float* __restrict__ pred,
    const float* __restrict__ target,
    float* __restrict__ partial) {
  __shared__ float lds[WAVES][64 * FPC];   // 7680 B per wave region
  __shared__ float wsum[WAVES];

  const int tid = threadIdx.x;
  const int lane = tid & 63;
  const int wid = tid >> 6;
  const int cellw = blockIdx.x * BLK + wid * 64;  // wave's first cell
  const int cell = cellw + lane;

  float* myld = lds[wid];
  union Buf { float2 v[FPC / 2]; float f[FPC]; };
  Buf P, T;

  // ---- stage pred tile: dense 16B NT loads, wave-private ----
  {
    const vfloat4* g = (const vfloat4*)(pred + (size_t)cellw * FPC);
    vfloat4* l = (vfloat4*)myld;
    #pragma unroll
    for (int it = 0; it < (TILE_F4 + 63) / 64; ++it) {
      int idx = it * 64 + lane;
      if (idx < TILE_F4) l[idx] = __builtin_nontemporal_load(g + idx);
    }
  }
  {
    const float2* l2 = (const float2*)(myld + lane * FPC);
    #pragma unroll
    for (int i = 0; i < FPC / 2; ++i) P.v[i] = l2[i];
  }
  asm volatile("" ::: "memory");  // keep target-stage writes after pred reads
  // ---- stage target tile into the SAME region (in-order per wave) ----
  {
    const vfloat4* g = (const vfloat4*)(target + (size_t)cellw * FPC);
    vfloat4* l = (vfloat4*)myld;
    #pragma unroll
    for (int it = 0; it < (TILE_F4 + 63) / 64; ++it) {
      int idx = it * 64 + lane;
      if (idx < TILE_F4) l[idx] = __builtin_nontemporal_load(g + idx);
    }
  }
  {
    const float2* l2 = (const float2*)(myld + lane * FPC);
    #pragma unroll
    for (int i = 0; i < FPC / 2; ++i) T.v[i] = l2[i];
  }

  const float* p = P.f;
  const float* t = T.f;

  // ---- per-cell loss ----
  const float gx = (float)(cell % S);
  const float gy = (float)((cell / S) % S);
  const float mask = (t[9] > 0.0f) ? 1.0f : 0.0f;

  float iou[2];
  #pragma unroll
  for (int b = 0; b < 2; ++b) {
    const float* pb = p + 5 * b;
    const float* tb = t + 5 * b;
    // _convert_boxes: x0=(x+gx)*STEP - w/2, clip all 4 at 0
    float px = fmaxf((pb[0] + gx) * STEP - pb[2] * 0.5f, 0.0f);
    float py = fmaxf((pb[1] + gy) * STEP - pb[3] * 0.5f, 0.0f);
    float pw = fmaxf(pb[2], 0.0f);
    float ph = fmaxf(pb[3], 0.0f);
    float tx = fmaxf((tb[0] + gx) * STEP - tb[2] * 0.5f, 0.0f);
    float ty = fmaxf((tb[1] + gy) * STEP - tb[3] * 0.5f, 0.0f);
    float tw = fmaxf(tb[2], 0.0f);
    float th = fmaxf(tb[3], 0.0f);
    float iw = fmaxf(pw + tw - (fmaxf(px + pw, tx + tw) - fminf(px, tx)), 0.0f);
    float ih = fmaxf(ph + th - (fmaxf(py + ph, ty + th) - fminf(py, ty)), 0.0f);
    float inter = iw * ih;
    float uni = pw * ph + tw * th - inter;
    iou[b] = inter / (uni + EPS);
  }
  // jnp.argmax: first max wins → box 0 on tie
  const int best = (iou[1] > iou[0]) ? 1 : 0;

  float loss = 0.0f;
  #pragma unroll
  for (int b = 0; b < 2; ++b) {
    const float* pb = p + 5 * b;
    const float* tb = t + 5 * b;
    float obj = (b == best) ? mask : 0.0f;
    float d0 = pb[0] - tb[0];
    float d1 = pb[1] - tb[1];
    float d2 = pb[2] - tb[2];
    float d3 = pb[3] - tb[3];
    loss += 5.0f * obj * (d0 * d0 + d1 * d1 + d2 * d2 + d3 * d3);  // coord
    float dc = pb[4] - iou[b];
    loss += obj * dc * dc;                                         // conf
    loss += 0.5f * (1.0f - obj) * pb[4] * pb[4];                   // noobj
  }
  float cls = 0.0f;
  #pragma unroll
  for (int k = 10; k < 30; ++k) {
    float d = p[k] - t[k];
    cls += d * d;
  }
  loss += mask * cls;                                              // class

  // ---- reduce: wave shuffle → LDS → one plain store per block ----
  #pragma unroll
  for (int off = 32; off > 0; off >>= 1)
    loss += __shfl_down(loss, off, 64);
  if ((tid & 63) == 0) wsum[wid] = loss;
  __syncthreads();
  if (tid == 0) {
    float total = 0.0f;
    #pragma unroll
    for (int w = 0; w < WAVES; ++w) total += wsum[w];
    partial[blockIdx.x] = total;          // distinct address — no atomic
  }
}

__global__ __launch_bounds__(256) void yolo_reduce_kernel(
    const float* __restrict__ partial, float* __restrict__ out,
    int n, float invN) {
  __shared__ float wsum[4];
  const int tid = threadIdx.x;
  float s = 0.0f;
  for (int i = tid; i < n; i += 256) s += partial[i];
  #pragma unroll
  for (int off = 32; off > 0; off >>= 1)
    s += __shfl_down(s, off, 64);
  if ((tid & 63) == 0) wsum[tid >> 6] = s;
  __syncthreads();
  if (tid == 0)
    out[0] = (wsum[0] + wsum[1] + wsum[2] + wsum[3]) * invN;
}

extern "C" void kernel_launch(void* const* d_in, const int* in_sizes, int n_in,
                              void* d_out, int out_size, void* d_ws, size_t ws_size,
                              hipStream_t stream) {
  const float* pred = (const float*)d_in[0];
  const float* target = (const float*)d_in[1];
  float* out = (float*)d_out;
  float* partial = (float*)d_ws;             // 3136 floats = 12.5 KB

  const int ncells = in_sizes[0] / FPC;      // 802816
  const int nblocks = ncells / BLK;          // 3136 (exact)
  const float invN = 1.0f / (float)(ncells / (S * S));  // 1/16384

  yolo_partial_kernel<<<nblocks, BLK, 0, stream>>>(pred, target, partial);
  yolo_reduce_kernel<<<1, 256, 0, stream>>>(partial, out, nblocks, invN);
}